// Round 9
// baseline (237.770 us; speedup 1.0000x reference)
//
#include <hip/hip_runtime.h>

// SpriteAssembler via MFMA, operand-swapped, identity-folded:
//   ACC[64i][16px] = W'[64i][64k] x B[64k][16px]   (f16 in, f32 acc)
// W part:   W[i][j] = tanh(relu(d_j - d_i)),  B[j][px] = log2(1 - s[px][j])
// id part:  acc[it] += Id x log2(s)  -- one extra MFMA per 16-row i-tile.
// masks = exp2(ACC) row-normalized (+eps).
// R9: attack per-tile serial latency. (1) shfl-reduce ELIMINATED: write
//     unnormalized u through the LDS transpose; after read-back each px-row
//     spans one 16-lane DPP row -> 64-i sum via 4 VALU row_ror adds (~16cy)
//     instead of 2 dependent ds_swizzle shfls (~240cy). (2) epilogue pipelined
//     one tile deep (double-buffered ustage): LDS-write t, compute t+1, then
//     read/reduce/store t -> LDS read latency hidden under next tile's MFMA.
//     Store path unchanged: 4 x 1KB lane-contiguous stores per tile.

typedef __attribute__((ext_vector_type(8))) _Float16 half8;
typedef __attribute__((ext_vector_type(4))) float floatx4;

#define EPSF 1e-6f

__device__ inline float fast_exp2(float x){ return __builtin_amdgcn_exp2f(x); }
__device__ inline float fast_log2(float x){ return __builtin_amdgcn_logf(x); }  // log2
__device__ inline float fast_rcp (float x){ return __builtin_amdgcn_rcpf(x); }

// x += row_ror<N>(x)  -- rotate within each 16-lane DPP row (VALU, no LDS)
template<int CTRL>
__device__ inline float dpp_add(float x) {
    int t = __builtin_amdgcn_update_dpp(0, __float_as_int(x), CTRL, 0xF, 0xF, true);
    return x + __int_as_float(t);
}
// full 16-lane row sum via rotate-reduce: ror 1,2,4,8
__device__ inline float row_sum16(float x) {
    x = dpp_add<0x121>(x);   // row_ror:1
    x = dpp_add<0x122>(x);   // row_ror:2
    x = dpp_add<0x124>(x);   // row_ror:4
    x = dpp_add<0x128>(x);   // row_ror:8
    return x;
}

__global__ __launch_bounds__(256, 2) void sprite_mfma_kernel(
    const float* __restrict__ shapes,   // [8, 65536, 64]
    const float* __restrict__ depths,   // [8, 64]
    float* __restrict__ out)            // [8, 65536, 64]
{
    const int wave  = threadIdx.x >> 6;
    const int lane  = threadIdx.x & 63;
    const int batch = blockIdx.x >> 7;   // 128 blocks per batch
    const int rblk  = blockIdx.x & 127;
    const int wid   = rblk * 4 + wave;   // wave id within batch [0,512), 128 px each

    __shared__ float dsh[64];
    __shared__ __align__(16) float ustage[4][2][16][68];  // [wave][buf][px][i] +4 pad

    if (threadIdx.x < 64) dsh[threadIdx.x] = depths[batch * 64 + threadIdx.x];
    __syncthreads();

    const int c = lane & 15;   // A: m(i-local). B: n(px). D: col(px)
    const int q = lane >> 4;   // k-quad / D row group

    // ---- W fragments (A-operand), built once per wave, amortized over 128 px ----
    half8 Aw[4][2];
    #pragma unroll
    for (int it = 0; it < 4; ++it) {
        float di = dsh[it * 16 + c];
        #pragma unroll
        for (int kt = 0; kt < 2; ++kt) {
            half8 h;
            #pragma unroll
            for (int jj = 0; jj < 8; ++jj) {
                int j = kt * 32 + q * 8 + jj;
                float x = fmaxf(dsh[j] - di, 0.0f);            // relu(d_j - d_i)
                float e = fast_exp2(x * 2.885390082f);         // e^{2x}
                h[jj] = (_Float16)((e - 1.0f) * fast_rcp(e + 1.0f));  // tanh
            }
            Aw[it][kt] = h;
        }
    }

    // identity A-fragments: nonzero only where k_local == (it&1)*16 + m
    half8 idlo, idhi;
    #pragma unroll
    for (int jj = 0; jj < 8; ++jj) {
        idlo[jj] = (q * 8 + jj == c)      ? (_Float16)1.0f : (_Float16)0.0f;
        idhi[jj] = (q * 8 + jj == 16 + c) ? (_Float16)1.0f : (_Float16)0.0f;
    }

    const long pxbase = (long)batch * 65536 + (long)wid * 128;
    const float* sp = shapes + (pxbase + c) * 64 + q * 8;  // lane's row chunk, tile 0
    float* const obase0 = out + pxbase * 64;               // wave's contiguous 32KB

    // B-layout loads: lane reads s[px=c][q*8 .. q*8+7] and the +32 block.
    float4 pf0 = *(const float4*)(sp);
    float4 pf1 = *(const float4*)(sp + 4);
    float4 pf2 = *(const float4*)(sp + 32);
    float4 pf3 = *(const float4*)(sp + 36);

    // ---- compute phase: MFMA + exp2, write UNNORMALIZED u to ustage[buf] ----
    auto compute = [&](int tile, int buf) {
        float4 s0 = pf0, s1 = pf1, s2 = pf2, s3 = pf3;
        if (tile < 7) {                          // software prefetch next tile
            const float* sn = sp + (tile + 1) * 16 * 64;
            pf0 = *(const float4*)(sn);
            pf1 = *(const float4*)(sn + 4);
            pf2 = *(const float4*)(sn + 32);
            pf3 = *(const float4*)(sn + 36);
        }

        float sv[16] = {s0.x, s0.y, s0.z, s0.w, s1.x, s1.y, s1.z, s1.w,
                        s2.x, s2.y, s2.z, s2.w, s3.x, s3.y, s3.z, s3.w};
        half8 B_lo, B_hi;                        // B[j][px=c]  = log2(1 - s)
        half8 C_lo, C_hi;                        // B2[j][px=c] = log2(s)
        #pragma unroll
        for (int e = 0; e < 8; ++e) {
            float slo = fminf(fmaxf(sv[e],     EPSF), 1.0f - EPSF);
            float shi = fminf(fmaxf(sv[8 + e], EPSF), 1.0f - EPSF);
            B_lo[e] = (_Float16)fast_log2(1.0f - slo);
            B_hi[e] = (_Float16)fast_log2(1.0f - shi);
            C_lo[e] = (_Float16)fast_log2(slo);
            C_hi[e] = (_Float16)fast_log2(shi);
        }

        floatx4 acc[4];
        #pragma unroll
        for (int it = 0; it < 4; ++it) {
            floatx4 a = {0.f, 0.f, 0.f, 0.f};
            a = __builtin_amdgcn_mfma_f32_16x16x32_f16(Aw[it][0], B_lo, a, 0, 0, 0);
            a = __builtin_amdgcn_mfma_f32_16x16x32_f16(Aw[it][1], B_hi, a, 0, 0, 0);
            a = __builtin_amdgcn_mfma_f32_16x16x32_f16(
                    (it & 1) ? idhi : idlo, (it < 2) ? C_lo : C_hi, a, 0, 0, 0);
            acc[it] = a;
        }

        // D layout: value (it, r) is ACC[i = it*16 + q*4 + r][px = tile*16 + c]
        // write row px=c, i-cols it*16+q*4 .. +4 (unnormalized)
        #pragma unroll
        for (int it = 0; it < 4; ++it) {
            floatx4 o = {fast_exp2(acc[it][0]), fast_exp2(acc[it][1]),
                         fast_exp2(acc[it][2]), fast_exp2(acc[it][3])};
            *(floatx4*)&ustage[wave][buf][c][it * 16 + q * 4] = o;
        }
    };

    // ---- epilogue phase: transpose read-back, DPP row-sum, normalize, store ----
    auto epilogue = [&](int tile, int buf) {
        float* ob = obase0 + (long)tile * 16 * 64;
        #pragma unroll
        for (int k = 0; k < 4; ++k) {
            // lane holds px = tile*16 + k*4 + q, i-cols c*4 .. +4
            floatx4 v = *(const floatx4*)&ustage[wave][buf][k * 4 + q][c * 4];
            float s = (v[0] + v[1]) + (v[2] + v[3]);
            s = row_sum16(s);                    // sum over all 16 c-lanes (64 i)
            float inv = fast_rcp(s + EPSF);
            floatx4 o = {v[0] * inv, v[1] * inv, v[2] * inv, v[3] * inv};
            *(floatx4*)(ob + k * 256 + lane * 4) = o;  // 1KB lane-contiguous
        }
    };

    // ---- 1-deep epilogue pipeline: LDS latency hidden under next compute ----
    compute(0, 0);
    compute(1, 1); epilogue(0, 0);
    compute(2, 0); epilogue(1, 1);
    compute(3, 1); epilogue(2, 0);
    compute(4, 0); epilogue(3, 1);
    compute(5, 1); epilogue(4, 0);
    compute(6, 0); epilogue(5, 1);
    compute(7, 1); epilogue(6, 0);
    epilogue(7, 1);
}

extern "C" void kernel_launch(void* const* d_in, const int* in_sizes, int n_in,
                              void* d_out, int out_size, void* d_ws, size_t ws_size,
                              hipStream_t stream) {
    const float* shapes = (const float*)d_in[0];
    const float* depths = (const float*)d_in[1];
    float* out = (float*)d_out;
    // 8 batches * 128 blocks, 256 threads (4 waves), 128 px per wave
    sprite_mfma_kernel<<<1024, 256, 0, stream>>>(shapes, depths, out);
}